// Round 8
// baseline (390.101 us; speedup 1.0000x reference)
//
#include <hip/hip_runtime.h>
#include <cstddef>

#define BB    16
#define NN    2048
#define BN    (BB * NN)
#define PAIRS (BN / 2)          // row-pairs across all batches
#define EPSF  1e-9f
#define TPB   512
#define CPT   2                 // columns (rows) per thread
#define SPLIT 16                // reduction-dim split
#define TILE  128               // NN/SPLIT rows (or cols) staged per block
#define CHUNK 1024              // TPB*CPT columns (rows) per block
#define K9C   4                 // k9 kernel: 512 threads x 4 = 2048

typedef float v2f __attribute__((ext_vector_type(2)));
typedef float v4f __attribute__((ext_vector_type(4)));

// OCML native exp2 is always linkable; builtin preferred (both -> v_exp_f32).
extern "C" __device__ float __ocml_native_exp2_f32(float);
__device__ __forceinline__ float fast_exp2(float x) {
#if __has_builtin(__builtin_amdgcn_exp2f)
    return __builtin_amdgcn_exp2f(x);
#else
    return __ocml_native_exp2_f32(x);
#endif
}

// Packed fp32 (VOP3P): 2 IEEE fp32 ops per VALU issue slot.
__device__ __forceinline__ v2f pk_fma(v2f a, v2f b, v2f c) {
    v2f d;
    asm("v_pk_fma_f32 %0, %1, %2, %3" : "=v"(d) : "v"(a), "v"(b), "v"(c));
    return d;
}
__device__ __forceinline__ v2f pk_add(v2f a, v2f b) {
    v2f d;
    asm("v_pk_add_f32 %0, %1, %2" : "=v"(d) : "v"(a), "v"(b));
    return d;
}
__device__ __forceinline__ v2f pk_mul(v2f a, v2f b) {
    v2f d;
    asm("v_pk_mul_f32 %0, %1, %2" : "=v"(d) : "v"(a), "v"(b));
    return d;
}

__device__ __forceinline__ float block_sum(float v, int t, float* tmp8) {
#pragma unroll
    for (int o = 32; o > 0; o >>= 1) v += __shfl_down(v, o, 64);
    __syncthreads();                       // protect tmp8 reuse across calls
    if ((t & 63) == 0) tmp8[t >> 6] = v;
    __syncthreads();
    float s = 0.0f;
#pragma unroll
    for (int w = 0; w < TPB / 64; w++) s += tmp8[w];
    return s;
}

// preA: per row idx: cur_k = max(cur_{k-1}*(1-RS_{k-1}),0); out += cur*RR (k>0);
// zero RS/RR for this round's passB; write pair-interleaved row staging
// (exact image of R2's s_pa/s_pb/s_cu2) to global for passA's L1-broadcast reads.
__global__ void preA(
    const float* __restrict__ preds, const float* __restrict__ curprev,
    const float* __restrict__ RSprev, const float* __restrict__ RRprev,
    float* __restrict__ curout, float* __restrict__ RSz, float* __restrict__ RRz,
    v4f* __restrict__ stgA1, v4f* __restrict__ stgA2, v2f* __restrict__ stgAcu,
    float* __restrict__ out, float c1, int k)
{
    __shared__ float tmp8[TPB / 64];
    int t = threadIdx.x;
    int idx = blockIdx.x * TPB + t;            // 0..BN-1
    const float* p = preds + (size_t)idx * 3;
    float px = p[0], py = p[1], pz = p[2];
    float pn = px * px + py * py + pz * pz;
    float cu, contrib = 0.0f;
    if (k == 0) cu = 1.0f;
    else {
        float cup = curprev[idx], rs = RSprev[idx], rr = RRprev[idx];
        contrib = cup * rr;                    // round k-1 result term
        cu = fmaxf(cup * (1.0f - rs), 0.0f);
    }
    curout[idx] = cu;
    RSz[idx] = 0.0f; RRz[idx] = 0.0f;
    int h = idx >> 1, par = idx & 1;
    float* a1 = (float*)&stgA1[h];
    float* a2 = (float*)&stgA2[h];
    a1[par] = px;  a1[2 + par] = py;
    a2[par] = pz;  a2[2 + par] = c1 * pn;
    ((float*)&stgAcu[h])[par] = cu;
    if (k > 0) {
        float s = block_sum(contrib, t, tmp8);
        if (t == 0) atomicAdd(out, s);
    }
}

// preB: per col idx: cc = cost*bw/D1 from (S,T,cost); write cost_{k+1};
// zero S/T for next round's passA; write pair-interleaved label staging.
__global__ void preB(
    const float* __restrict__ labels, const float* __restrict__ Sread,
    const float* __restrict__ Tread, const float* __restrict__ costprev,
    float* __restrict__ costout, float* __restrict__ Sz, float* __restrict__ Tz,
    v4f* __restrict__ stgB1, v4f* __restrict__ stgB2, v2f* __restrict__ stgBcc,
    float c1, int k)
{
    int idx = blockIdx.x * TPB + threadIdx.x;
    const float* l = labels + (size_t)idx * 3;
    float lx = l[0], ly = l[1], lz = l[2];
    float lm2 = lx * lx + ly * ly + lz * lz;
    float S = Sread[idx], T = Tread[idx];
    float cost = (k == 0) ? 1.0f : costprev[idx];
    float D1 = fmaf(cost, S, EPSF);
    float S2 = cost * T / D1;
    float bw = fminf(cost / (S2 + EPSF), 1.0f);
    float cc = cost * bw / D1;
    costout[idx] = fmaxf(fmaf(-S2, bw, cost), 0.0f);
    Sz[idx] = 0.0f; Tz[idx] = 0.0f;
    int h = idx >> 1, par = idx & 1;
    float n2c1 = -2.0f * c1;
    float* b1 = (float*)&stgB1[h];
    float* b2 = (float*)&stgB2[h];
    b1[par] = n2c1 * lx;  b1[2 + par] = n2c1 * ly;
    b2[par] = n2c1 * lz;  b2[2 + par] = c1 * lm2;
    ((float*)&stgBcc[h])[par] = cc;
}

// passA main: S[m] += sum_n e, T[m] += sum_n e*cu[n]. Row data comes from the
// global staging arrays via L1-broadcast loads (VMEM pipe) — NO LDS, no barrier.
__global__ __launch_bounds__(TPB, 4) void passA(
    const float* __restrict__ labels,
    const v4f* __restrict__ stgA1, const v4f* __restrict__ stgA2,
    const v2f* __restrict__ stgAcu,
    float* __restrict__ Sacc, float* __restrict__ Tacc, float c1)
{
    int blk = blockIdx.x;
    int split = blk & 15, mc = (blk >> 4) & 1, b = blk >> 5;
    int t = threadIdx.x;
    int base = b * NN;

    // thread-held columns (labels), prescaled by c1; coefficients as packed pairs
    int m0 = mc * CHUNK + t;
    v2f gx2[CPT], gy2[CPT], gz2[CPT], am2[CPT], Sa2[CPT], Ta2[CPT];
    float n2c1 = -2.0f * c1;
#pragma unroll
    for (int c = 0; c < CPT; c++) {
        int m = m0 + c * TPB;
        const float* l = labels + (size_t)(base + m) * 3;
        float lx = l[0], ly = l[1], lz = l[2];
        float gx = n2c1 * lx, gy = n2c1 * ly, gz = n2c1 * lz;
        float am = c1 * (lx * lx + ly * ly + lz * lz);
        gx2[c] = (v2f){gx, gx}; gy2[c] = (v2f){gy, gy}; gz2[c] = (v2f){gz, gz};
        am2[c] = (v2f){am, am};
        Sa2[c] = (v2f){0.0f, 0.0f}; Ta2[c] = (v2f){0.0f, 0.0f};
    }

    int pbase = b * (NN / 2) + split * (TILE / 2);
#pragma unroll 4
    for (int h = 0; h < TILE / 2; h++) {
        v4f A1 = stgA1[pbase + h];     // (x0,x1,y0,y1)
        v4f A2 = stgA2[pbase + h];     // (z0,z1,w0,w1)
        v2f cu2 = stgAcu[pbase + h];
#pragma unroll
        for (int c = 0; c < CPT; c++) {
            v2f seed = pk_add(A2.zw, am2[c]);
            v2f arg = pk_fma(A1.xy, gx2[c],
                      pk_fma(A1.zw, gy2[c],
                      pk_fma(A2.xy, gz2[c], seed)));
            v2f e2;
            e2.x = fast_exp2(arg.x);
            e2.y = fast_exp2(arg.y);
            Sa2[c] = pk_add(Sa2[c], e2);
            Ta2[c] = pk_fma(e2, cu2, Ta2[c]);
        }
    }
#pragma unroll
    for (int c = 0; c < CPT; c++) {
        int idx = base + m0 + c * TPB;
        atomicAdd(&Sacc[idx], Sa2[c].x + Sa2[c].y);
        atomicAdd(&Tacc[idx], Ta2[c].x + Ta2[c].y);
    }
}

// passB main: RS[n] += sum_m e*cc; RR[n] += sum_m e*cc*pw (via (sum w*arg)/c1).
__global__ __launch_bounds__(TPB, 4) void passB(
    const float* __restrict__ preds,
    const v4f* __restrict__ stgB1, const v4f* __restrict__ stgB2,
    const v2f* __restrict__ stgBcc,
    float* __restrict__ RSacc, float* __restrict__ RRacc,
    float c1, float invc1)
{
    int blk = blockIdx.x;
    int split = blk & 15, nc = (blk >> 4) & 1, b = blk >> 5;
    int t = threadIdx.x;
    int base = b * NN;

    int n0 = nc * CHUNK + t;
    v2f px2[CPT], py2[CPT], pz2[CPT], qq2[CPT], RSa2[CPT], RRa2[CPT];
#pragma unroll
    for (int c = 0; c < CPT; c++) {
        int n = n0 + c * TPB;
        const float* p = preds + (size_t)(base + n) * 3;
        float px = p[0], py = p[1], pz = p[2];
        float qq = c1 * (px * px + py * py + pz * pz);
        px2[c] = (v2f){px, px}; py2[c] = (v2f){py, py}; pz2[c] = (v2f){pz, pz};
        qq2[c] = (v2f){qq, qq};
        RSa2[c] = (v2f){0.0f, 0.0f}; RRa2[c] = (v2f){0.0f, 0.0f};
    }

    int pbase = b * (NN / 2) + split * (TILE / 2);
#pragma unroll 4
    for (int h = 0; h < TILE / 2; h++) {
        v4f L1 = stgB1[pbase + h];
        v4f L2 = stgB2[pbase + h];
        v2f cc2 = stgBcc[pbase + h];
#pragma unroll
        for (int c = 0; c < CPT; c++) {
            v2f seed = pk_add(L2.zw, qq2[c]);
            v2f arg = pk_fma(L1.xy, px2[c],
                      pk_fma(L1.zw, py2[c],
                      pk_fma(L2.xy, pz2[c], seed)));
            v2f e2;
            e2.x = fast_exp2(arg.x);
            e2.y = fast_exp2(arg.y);
            v2f w2 = pk_mul(e2, cc2);
            RSa2[c] = pk_add(RSa2[c], w2);
            RRa2[c] = pk_fma(w2, arg, RRa2[c]);        // sum w*arg; *1/c1 at end
        }
    }
#pragma unroll
    for (int c = 0; c < CPT; c++) {
        int idx = base + n0 + c * TPB;
        atomicAdd(&RSacc[idx], RSa2[c].x + RSa2[c].y);
        atomicAdd(&RRacc[idx], (RRa2[c].x + RRa2[c].y) * invc1);
    }
}

// Round 9 (ef=0 -> e==1 exactly) collapses algebraically:
//   RR9[n] = A*|p_n|^2 + B - 2 p_n.V;  A=sum cc, B=sum cc*|l|^2, V=sum cc*l
//   out += sum cur8*RR8 + sum cur9*RR9
__global__ __launch_bounds__(TPB, 1) void k9(
    const float* __restrict__ preds, const float* __restrict__ labels,
    const float* __restrict__ cur8, const float* __restrict__ RS8,
    const float* __restrict__ RR8, const float* __restrict__ cost9,
    float* __restrict__ out)
{
    __shared__ float tmp8[TPB / 64];
    int b = blockIdx.x, t = threadIdx.x;
    int base = b * NN;

    float cu9[K9C];
    float contrib = 0.0f, csum = 0.0f;
#pragma unroll
    for (int c = 0; c < K9C; c++) {
        int idx = base + t + c * TPB;
        float cup = cur8[idx];
        contrib = fmaf(cup, RR8[idx], contrib);       // round-8 result term
        float cu = fmaxf(cup * (1.0f - RS8[idx]), 0.0f);
        cu9[c] = cu; csum += cu;
    }
    float contribT = block_sum(contrib, t, tmp8);
    float Cb = block_sum(csum, t, tmp8);              // T[m] == Cb for all m

    float A = 0.0f, Bs = 0.0f, Vx = 0.0f, Vy = 0.0f, Vz = 0.0f;
#pragma unroll
    for (int c = 0; c < K9C; c++) {
        int idx = base + t + c * TPB;
        const float* l = labels + (size_t)idx * 3;
        float lx = l[0], ly = l[1], lz = l[2];
        float cost = cost9[idx];
        float D1 = fmaf(cost, 2048.0f, EPSF);         // S == 2048 exactly
        float S2 = cost * Cb / D1;
        float bw = fminf(cost / (S2 + EPSF), 1.0f);
        float cc = cost * bw / D1;
        A += cc;
        Bs = fmaf(cc, lx * lx + ly * ly + lz * lz, Bs);
        Vx = fmaf(cc, lx, Vx); Vy = fmaf(cc, ly, Vy); Vz = fmaf(cc, lz, Vz);
    }
    float At  = block_sum(A, t, tmp8);
    float Bt  = block_sum(Bs, t, tmp8);
    float Vxt = block_sum(Vx, t, tmp8);
    float Vyt = block_sum(Vy, t, tmp8);
    float Vzt = block_sum(Vz, t, tmp8);

    float acc = 0.0f;
#pragma unroll
    for (int c = 0; c < K9C; c++) {
        int idx = base + t + c * TPB;
        const float* p = preds + (size_t)idx * 3;
        float x = p[0], y = p[1], z = p[2];
        float pn = x * x + y * y + z * z;
        float rr = fmaf(At, pn, Bt) - 2.0f * (x * Vxt + y * Vyt + z * Vzt);
        acc = fmaf(cu9[c], rr, acc);                  // round-9 result term
    }
    float accT = block_sum(acc, t, tmp8);
    if (t == 0) atomicAdd(out, contribT + accT);
}

extern "C" void kernel_launch(void* const* d_in, const int* in_sizes, int n_in,
                              void* d_out, int out_size, void* d_ws, size_t ws_size,
                              hipStream_t stream) {
    const float* preds  = (const float*)d_in[0];
    const float* labels = (const float*)d_in[1];
    float* out = (float*)d_out;
    float* ws  = (float*)d_ws;

    // layout: S0 T0 S1 T1 RS0 RR0 RS1 RR1 cur0 cur1 cost0 cost1  (12*BN floats)
    float* S[2]     = {ws + 0 * BN, ws + 2 * BN};
    float* T[2]     = {ws + 1 * BN, ws + 3 * BN};
    float* RS[2]    = {ws + 4 * BN, ws + 6 * BN};
    float* RR[2]    = {ws + 5 * BN, ws + 7 * BN};
    float* curb[2]  = {ws + 8 * BN, ws + 9 * BN};
    float* costb[2] = {ws + 10 * BN, ws + 11 * BN};
    // staging arrays (pair-interleaved row/col images), after the 12 BN arrays
    float* sb = ws + 12 * BN;                 // 16B-aligned (12*BN*4 = 1.5MB)
    v4f* stgA1  = (v4f*)sb;                   // PAIRS v4f
    v4f* stgA2  = stgA1 + PAIRS;
    v2f* stgAcu = (v2f*)(stgA2 + PAIRS);      // PAIRS v2f
    v4f* stgB1  = (v4f*)(stgAcu + PAIRS);
    v4f* stgB2  = stgB1 + PAIRS;
    v2f* stgBcc = (v2f*)(stgB2 + PAIRS);

    hipMemsetAsync(d_out, 0, sizeof(float), stream);
    hipMemsetAsync(ws, 0, (size_t)2 * BN * sizeof(float), stream);  // S[0], T[0]

    static const float efs[9] = {-16384.0f, -4096.0f, -1024.0f, -256.0f, -64.0f,
                                 -16.0f, -4.0f, -1.0f, -0.25f};
    const float log2e = 1.44269504088896f;
    for (int k = 0; k < 9; k++) {
        float c1 = efs[k] * log2e;
        float invc1 = 1.0f / c1;
        int pk = k & 1, pp = (k + 1) & 1;   // pp == (k-1)&1 for k>=1
        preA<<<BN / TPB, TPB, 0, stream>>>(preds,
            curb[pp], RS[pp], RR[pp],       // prev round's state
            curb[pk], RS[pk], RR[pk],       // cur_k out; zero for this passB
            stgA1, stgA2, stgAcu, out, c1, k);
        passA<<<512, TPB, 0, stream>>>(labels,
            stgA1, stgA2, stgAcu,
            S[pk], T[pk], c1);
        preB<<<BN / TPB, TPB, 0, stream>>>(labels,
            S[pk], T[pk],
            costb[pk], costb[pp],           // cost_k -> cost_{k+1}
            S[pp], T[pp],                   // zero for next round's passA
            stgB1, stgB2, stgBcc, c1, k);
        passB<<<512, TPB, 0, stream>>>(preds,
            stgB1, stgB2, stgBcc,
            RS[pk], RR[pk], c1, invc1);
    }
    // after k=8: cur8=curb[0], RS8=RS[0], RR8=RR[0], cost9=costb[1]
    k9<<<BB, TPB, 0, stream>>>(preds, labels, curb[0], RS[0], RR[0], costb[1], out);
}

// Round 9
// 320.647 us; speedup vs baseline: 1.2166x; 1.2166x over previous
//
#include <hip/hip_runtime.h>
#include <cstddef>

#define BB    16
#define NN    2048
#define BN    (BB * NN)
#define EPSF  1e-9f
#define TPB   512
#define CPT   2                 // columns (rows) per thread
#define SPLIT 32                // reduction-dim split
#define TILE  64                // NN/SPLIT rows (or cols) staged per block
#define CHUNK 1024              // TPB*CPT columns (rows) per block
#define GRID  (SPLIT * 2 * BB)  // 1024 blocks -> 4 blocks/CU -> 32 waves/CU
#define K9C   4                 // k9 kernel: 512 threads x 4 = 2048

// OCML native exp2 is always linkable; builtin preferred (both -> v_exp_f32).
extern "C" __device__ float __ocml_native_exp2_f32(float);
__device__ __forceinline__ float fast_exp2(float x) {
#if __has_builtin(__builtin_amdgcn_exp2f)
    return __builtin_amdgcn_exp2f(x);
#else
    return __ocml_native_exp2_f32(x);
#endif
}

__device__ __forceinline__ float block_sum(float v, int t, float* tmp8) {
#pragma unroll
    for (int o = 32; o > 0; o >>= 1) v += __shfl_down(v, o, 64);
    __syncthreads();                       // protect tmp8 reuse across calls
    if ((t & 63) == 0) tmp8[t >> 6] = v;
    __syncthreads();
    float s = 0.0f;
#pragma unroll
    for (int w = 0; w < TPB / 64; w++) s += tmp8[w];
    return s;
}

// passA (fused with prev round's combB):
//   prologue: cur_k = max(cur_{k-1}*(1-RS_{k-1}),0); out += sum cur_{k-1}*RR_{k-1};
//             zero RS/RR[k&1] for this round's passB; write cur_k (mc==0 blocks).
//   main:     S[m] += sum_n e, T[m] += sum_n e*cur_k[n]   (atomic partials)
// Occupancy build: scalar math (no VOP3P asm -> pressure-safe), TILE=64,
// grid 1024, 8 waves/SIMD via __launch_bounds__(512,8).
__global__ __launch_bounds__(TPB, 8) void passA(
    const float* __restrict__ preds, const float* __restrict__ labels,
    const float* __restrict__ curprev, float* __restrict__ curout,
    const float* __restrict__ RSprev, const float* __restrict__ RRprev,
    float* __restrict__ RSz, float* __restrict__ RRz,
    float* __restrict__ Sacc, float* __restrict__ Tacc,
    float* __restrict__ out, float c1, int k)
{
    __shared__ float4 s_p[TILE];   // (px,py,pz, c1*|p|^2)
    __shared__ float  s_cu[TILE];
    __shared__ float  s_red0;
    int blk = blockIdx.x;
    int split = blk & 31, mc = (blk >> 5) & 1, b = blk >> 6;
    int t = threadIdx.x;
    int base = b * NN;

    if (t < TILE) {                        // exactly wave 0
        int idx = base + split * TILE + t;
        const float* p = preds + (size_t)idx * 3;
        float px = p[0], py = p[1], pz = p[2];
        float pn = px * px + py * py + pz * pz;
        float cu, contrib = 0.0f;
        if (k == 0) cu = 1.0f;
        else {
            float cup = curprev[idx], rs = RSprev[idx], rr = RRprev[idx];
            contrib = cup * rr;                       // round k-1 result term
            cu = fmaxf(cup * (1.0f - rs), 0.0f);
        }
        s_p[t]  = make_float4(px, py, pz, c1 * pn);
        s_cu[t] = cu;
        if (mc == 0) {
            curout[idx] = cu;
            RSz[idx] = 0.0f; RRz[idx] = 0.0f;         // for this round's passB
        }
        if (k > 0) {                                  // single wave: shuffle only
#pragma unroll
            for (int o = 32; o > 0; o >>= 1) contrib += __shfl_down(contrib, o, 64);
            if (t == 0) s_red0 = contrib;
        }
    }

    // thread-held columns (labels), prescaled by c1
    int m0 = mc * CHUNK + t;
    float gx[CPT], gy[CPT], gz[CPT], am[CPT], Sa[CPT], Ta[CPT];
    float n2c1 = -2.0f * c1;
#pragma unroll
    for (int c = 0; c < CPT; c++) {
        int m = m0 + c * TPB;
        const float* l = labels + (size_t)(base + m) * 3;
        float lx = l[0], ly = l[1], lz = l[2];
        gx[c] = n2c1 * lx; gy[c] = n2c1 * ly; gz[c] = n2c1 * lz;
        am[c] = c1 * (lx * lx + ly * ly + lz * lz);
        Sa[c] = 0.0f; Ta[c] = 0.0f;
    }
    __syncthreads();
    if (k > 0 && mc == 0 && t == 0) atomicAdd(out, s_red0);

#pragma unroll 4
    for (int j = 0; j < TILE; j++) {
        float4 P = s_p[j]; float cu = s_cu[j];
#pragma unroll
        for (int c = 0; c < CPT; c++) {
            float arg = fmaf(P.x, gx[c], fmaf(P.y, gy[c], fmaf(P.z, gz[c], P.w + am[c])));
            float e = fast_exp2(arg);
            Sa[c] += e;
            Ta[c] = fmaf(e, cu, Ta[c]);
        }
    }
#pragma unroll
    for (int c = 0; c < CPT; c++) {
        int idx = base + m0 + c * TPB;
        atomicAdd(&Sacc[idx], Sa[c]);
        atomicAdd(&Tacc[idx], Ta[c]);
    }
}

// passB (fused with combA):
//   prologue: per staged column m: cc = cost*bw/D1 (from S,T,cost); nc==0 blocks
//             write cost_{k+1}, zero S/T[(k+1)&1] for next round's passA.
//   main:     RS[n] += sum_m e*cc; RR[n] += sum_m e*cc*pw (via (sum w*arg)/c1).
__global__ __launch_bounds__(TPB, 8) void passB(
    const float* __restrict__ preds, const float* __restrict__ labels,
    const float* __restrict__ Sread, const float* __restrict__ Tread,
    const float* __restrict__ costprev, float* __restrict__ costout,
    float* __restrict__ Sz, float* __restrict__ Tz,
    float* __restrict__ RSacc, float* __restrict__ RRacc,
    float c1, float invc1, int k)
{
    __shared__ float4 s_l[TILE];   // (-2c1*lx, -2c1*ly, -2c1*lz, c1*|l|^2)
    __shared__ float  s_cc[TILE];
    int blk = blockIdx.x;
    int split = blk & 31, nc = (blk >> 5) & 1, b = blk >> 6;
    int t = threadIdx.x;
    int base = b * NN;

    if (t < TILE) {                        // exactly wave 0
        int idx = base + split * TILE + t;
        const float* l = labels + (size_t)idx * 3;
        float lx = l[0], ly = l[1], lz = l[2];
        float lm2 = lx * lx + ly * ly + lz * lz;
        float S = Sread[idx], T = Tread[idx];
        float cost = (k == 0) ? 1.0f : costprev[idx];
        float D1 = fmaf(cost, S, EPSF);
        float S2 = cost * T / D1;
        float bw = fminf(cost / (S2 + EPSF), 1.0f);
        float cc = cost * bw / D1;
        float n2c1 = -2.0f * c1;
        s_l[t]  = make_float4(n2c1 * lx, n2c1 * ly, n2c1 * lz, c1 * lm2);
        s_cc[t] = cc;
        if (nc == 0) {
            costout[idx] = fmaxf(fmaf(-S2, bw, cost), 0.0f);
            Sz[idx] = 0.0f; Tz[idx] = 0.0f;            // for next round's passA
        }
    }

    int n0 = nc * CHUNK + t;
    float px[CPT], py[CPT], pz[CPT], qq[CPT], RSa[CPT], RRa[CPT];
#pragma unroll
    for (int c = 0; c < CPT; c++) {
        int n = n0 + c * TPB;
        const float* p = preds + (size_t)(base + n) * 3;
        px[c] = p[0]; py[c] = p[1]; pz[c] = p[2];
        qq[c] = c1 * (px[c] * px[c] + py[c] * py[c] + pz[c] * pz[c]);
        RSa[c] = 0.0f; RRa[c] = 0.0f;
    }
    __syncthreads();

#pragma unroll 4
    for (int j = 0; j < TILE; j++) {
        float4 L = s_l[j]; float ccj = s_cc[j];
#pragma unroll
        for (int c = 0; c < CPT; c++) {
            float arg = fmaf(px[c], L.x, fmaf(py[c], L.y, fmaf(pz[c], L.z, qq[c] + L.w)));
            float e = fast_exp2(arg);
            float w = e * ccj;
            RSa[c] += w;
            RRa[c] = fmaf(w, arg, RRa[c]);             // sum w*arg; *1/c1 at end
        }
    }
#pragma unroll
    for (int c = 0; c < CPT; c++) {
        int idx = base + n0 + c * TPB;
        atomicAdd(&RSacc[idx], RSa[c]);
        atomicAdd(&RRacc[idx], RRa[c] * invc1);
    }
}

// Round 9 (ef=0 -> e==1 exactly) collapses algebraically:
//   RR9[n] = A*|p_n|^2 + B - 2 p_n.V;  A=sum cc, B=sum cc*|l|^2, V=sum cc*l
//   out += sum cur8*RR8 + sum cur9*RR9
__global__ __launch_bounds__(TPB, 1) void k9(
    const float* __restrict__ preds, const float* __restrict__ labels,
    const float* __restrict__ cur8, const float* __restrict__ RS8,
    const float* __restrict__ RR8, const float* __restrict__ cost9,
    float* __restrict__ out)
{
    __shared__ float tmp8[TPB / 64];
    int b = blockIdx.x, t = threadIdx.x;
    int base = b * NN;

    float cu9[K9C];
    float contrib = 0.0f, csum = 0.0f;
#pragma unroll
    for (int c = 0; c < K9C; c++) {
        int idx = base + t + c * TPB;
        float cup = cur8[idx];
        contrib = fmaf(cup, RR8[idx], contrib);       // round-8 result term
        float cu = fmaxf(cup * (1.0f - RS8[idx]), 0.0f);
        cu9[c] = cu; csum += cu;
    }
    float contribT = block_sum(contrib, t, tmp8);
    float Cb = block_sum(csum, t, tmp8);              // T[m] == Cb for all m

    float A = 0.0f, Bs = 0.0f, Vx = 0.0f, Vy = 0.0f, Vz = 0.0f;
#pragma unroll
    for (int c = 0; c < K9C; c++) {
        int idx = base + t + c * TPB;
        const float* l = labels + (size_t)idx * 3;
        float lx = l[0], ly = l[1], lz = l[2];
        float cost = cost9[idx];
        float D1 = fmaf(cost, 2048.0f, EPSF);         // S == 2048 exactly
        float S2 = cost * Cb / D1;
        float bw = fminf(cost / (S2 + EPSF), 1.0f);
        float cc = cost * bw / D1;
        A += cc;
        Bs = fmaf(cc, lx * lx + ly * ly + lz * lz, Bs);
        Vx = fmaf(cc, lx, Vx); Vy = fmaf(cc, ly, Vy); Vz = fmaf(cc, lz, Vz);
    }
    float At  = block_sum(A, t, tmp8);
    float Bt  = block_sum(Bs, t, tmp8);
    float Vxt = block_sum(Vx, t, tmp8);
    float Vyt = block_sum(Vy, t, tmp8);
    float Vzt = block_sum(Vz, t, tmp8);

    float acc = 0.0f;
#pragma unroll
    for (int c = 0; c < K9C; c++) {
        int idx = base + t + c * TPB;
        const float* p = preds + (size_t)idx * 3;
        float x = p[0], y = p[1], z = p[2];
        float pn = x * x + y * y + z * z;
        float rr = fmaf(At, pn, Bt) - 2.0f * (x * Vxt + y * Vyt + z * Vzt);
        acc = fmaf(cu9[c], rr, acc);                  // round-9 result term
    }
    float accT = block_sum(acc, t, tmp8);
    if (t == 0) atomicAdd(out, contribT + accT);
}

extern "C" void kernel_launch(void* const* d_in, const int* in_sizes, int n_in,
                              void* d_out, int out_size, void* d_ws, size_t ws_size,
                              hipStream_t stream) {
    const float* preds  = (const float*)d_in[0];
    const float* labels = (const float*)d_in[1];
    float* out = (float*)d_out;
    float* ws  = (float*)d_ws;

    // layout: S0 T0 S1 T1 RS0 RR0 RS1 RR1 cur0 cur1 cost0 cost1  (12*BN floats = 1.5 MB)
    float* S[2]     = {ws + 0 * BN, ws + 2 * BN};
    float* T[2]     = {ws + 1 * BN, ws + 3 * BN};
    float* RS[2]    = {ws + 4 * BN, ws + 6 * BN};
    float* RR[2]    = {ws + 5 * BN, ws + 7 * BN};
    float* curb[2]  = {ws + 8 * BN, ws + 9 * BN};
    float* costb[2] = {ws + 10 * BN, ws + 11 * BN};

    hipMemsetAsync(d_out, 0, sizeof(float), stream);
    hipMemsetAsync(ws, 0, (size_t)2 * BN * sizeof(float), stream);  // S[0], T[0]

    static const float efs[9] = {-16384.0f, -4096.0f, -1024.0f, -256.0f, -64.0f,
                                 -16.0f, -4.0f, -1.0f, -0.25f};
    const float log2e = 1.44269504088896f;
    for (int k = 0; k < 9; k++) {
        float c1 = efs[k] * log2e;
        float invc1 = 1.0f / c1;
        int pk = k & 1, pp = (k + 1) & 1;   // pp == (k-1)&1 for k>=1
        passA<<<GRID, TPB, 0, stream>>>(preds, labels,
            curb[pp], curb[pk],     // cur_{k-1} -> cur_k
            RS[pp], RR[pp],         // prev round's row sums
            RS[pk], RR[pk],         // zero for this round's passB
            S[pk], T[pk],           // accumulate this round's col sums
            out, c1, k);
        passB<<<GRID, TPB, 0, stream>>>(preds, labels,
            S[pk], T[pk],
            costb[pk], costb[pp],   // cost_k -> cost_{k+1}
            S[pp], T[pp],           // zero for next round's passA
            RS[pk], RR[pk],
            c1, invc1, k);
    }
    // after k=8: cur8=curb[0], RS8=RS[0], RR8=RR[0], cost9=costb[1]
    k9<<<BB, TPB, 0, stream>>>(preds, labels, curb[0], RS[0], RR[0], costb[1], out);
}